// Round 2
// baseline (254.622 us; speedup 1.0000x reference)
//
#include <hip/hip_runtime.h>

// B=8, H=W=48 -> 2304 positions, C=256 channels.
// raw[b,ij,kl] = sum_c A[b,ij,c]*B[b,kl,c]
// out = raw / sqrt(sum_ij raw^2)     (reference's 1/C cancels in the norm)
//
// R4: same Gram-trick algebra as R3 (colSq[kl] = B[kl]^T (A^T A) B[kl]) but
// the support kernels rebuilt for occupancy + dispatch count:
//   - gram: full-K per block -> no atomics, no memset, no fp32->bf16 pass
//   - colsq: 576 blocks, double-buffered, two slabs (cs0+cs1) -> no atomics
//   - corr_out: 128x256 tile, BK=32, double-buffered 2-phase (T3-minimum:
//     stage(t+1) issued BEFORE compute(t), one barrier per K-step)
// 4 dispatches total, zero memsets.

#define HW2 2304
#define CH  256
#define NB  8
#define NELEM (NB * HW2 * CH)   // 4,718,592 per input

typedef __attribute__((ext_vector_type(8))) short bf16x8;   // 8 bf16 = 4 VGPRs
typedef __attribute__((ext_vector_type(4))) float f32x4;    // MFMA acc

static __device__ inline unsigned short f2bf(float f) {
    union { float f; unsigned u; } x; x.f = f;
    unsigned r = x.u + 0x7FFFu + ((x.u >> 16) & 1u);
    return (unsigned short)(r >> 16);
}

static __device__ inline float bf2f(unsigned short u) {
    union { unsigned u; float f; } x; x.u = ((unsigned)u) << 16;
    return x.f;
}

// async global->LDS, 16B per lane (global_load_lds_dwordx4)
static __device__ inline void async_copy16(const void* g, void* l) {
    __builtin_amdgcn_global_load_lds(
        (const __attribute__((address_space(1))) unsigned int*)g,
        (__attribute__((address_space(3))) unsigned int*)l, 16, 0, 0);
}

// ---------------------------------------------------------------------------
// 1. convert: A,B fp32 -> bf16 row-major; additionally A^T (c-major) for gram.
// ---------------------------------------------------------------------------
__global__ __launch_bounds__(256) void convert_bf16(const float* __restrict__ A,
                                                    const float* __restrict__ B,
                                                    unsigned short* __restrict__ Abf,
                                                    unsigned short* __restrict__ Bbf,
                                                    unsigned short* __restrict__ Atbf) {
    __shared__ unsigned short t[64][65];   // +1 pad breaks transpose bank conflicts
    const int blk = blockIdx.x;            // 0..2303
    const bool isA = blk < 1152;
    const int tb = isA ? blk : blk - 1152;
    const int b  = tb / 144;               // 144 tiles per batch = 36 ij x 4 c
    const int tt = tb % 144;
    const int ijt = tt >> 2, ct = tt & 3;
    const size_t base = ((size_t)b * HW2 + (size_t)ijt * 64) * CH + ct * 64;
    const float* src = (isA ? A : B) + base;
    unsigned short* dst = (isA ? Abf : Bbf) + base;
    const int tid = threadIdx.x;
    const int lr = tid & 15, rq = tid >> 4;
#pragma unroll
    for (int p = 0; p < 4; p++) {
        const int row = rq + p * 16;
        float4 v = *(const float4*)(src + (size_t)row * CH + lr * 4);
        ushort4 u;
        u.x = f2bf(v.x); u.y = f2bf(v.y); u.z = f2bf(v.z); u.w = f2bf(v.w);
        *(ushort4*)(dst + (size_t)row * CH + lr * 4) = u;
        if (isA) {
            t[row][lr * 4 + 0] = u.x; t[row][lr * 4 + 1] = u.y;
            t[row][lr * 4 + 2] = u.z; t[row][lr * 4 + 3] = u.w;
        }
    }
    if (isA) {
        __syncthreads();
#pragma unroll
        for (int p = 0; p < 4; p++) {
            const int c = rq + p * 16;     // channel = transposed row
            ushort4 u;
            u.x = t[lr * 4 + 0][c]; u.y = t[lr * 4 + 1][c];
            u.z = t[lr * 4 + 2][c]; u.w = t[lr * 4 + 3][c];
            *(ushort4*)(Atbf + ((size_t)b * CH + (size_t)(ct * 64 + c)) * HW2
                        + (size_t)ijt * 64 + lr * 4) = u;
        }
    }
}

// ---------------------------------------------------------------------------
// 2. gram: G[b] = At . At^T, full K (2304) per block. 64x64 tiles, 128 blocks.
//    Double-buffered 2-phase. Writes bf16 G directly -> no atomics/memset.
// ---------------------------------------------------------------------------
__global__ __launch_bounds__(256) void gram(const unsigned short* __restrict__ Atbf,
                                            unsigned short* __restrict__ Gbf) {
    __shared__ unsigned short As[2][4096];   // [buf][c2*2048 + row*32 + k8]
    __shared__ unsigned short Bs[2][4096];
    const int tid = threadIdx.x;
    const int bx = blockIdx.x, by = blockIdx.y, b = blockIdx.z;
    const unsigned short* Ar = Atbf + ((size_t)b * CH + by * 64) * HW2;
    const unsigned short* Br = Atbf + ((size_t)b * CH + bx * 64) * HW2;
    const int srow = tid >> 2, skcol = (tid & 3) * 8;
    const int wave = tid >> 6, lane = tid & 63;
    const int wm = (wave >> 1) * 32, wn = (wave & 1) * 32;
    const int lr = lane & 15, quad = lane >> 4, k8 = quad * 8;

    f32x4 acc[2][2];
#pragma unroll
    for (int i = 0; i < 2; i++)
#pragma unroll
        for (int j = 0; j < 2; j++) acc[i][j] = (f32x4){0.f, 0.f, 0.f, 0.f};

#define G_STAGE(bufi, kt)                                                      \
    {                                                                          \
        _Pragma("unroll")                                                      \
        for (int c2 = 0; c2 < 2; c2++) {                                       \
            async_copy16(Ar + (size_t)srow * HW2 + (kt) + c2 * 32 + skcol,     \
                         &As[bufi][c2 * 2048 + tid * 8]);                      \
            async_copy16(Br + (size_t)srow * HW2 + (kt) + c2 * 32 + skcol,     \
                         &Bs[bufi][c2 * 2048 + tid * 8]);                      \
        }                                                                      \
    }

    G_STAGE(0, 0);
    __syncthreads();
    for (int t = 0; t < 36; t++) {
        const int buf = t & 1;
        if (t < 35) G_STAGE(buf ^ 1, (t + 1) * 64);
#pragma unroll
        for (int c2 = 0; c2 < 2; c2++) {
            bf16x8 af[2], bfr[2];
#pragma unroll
            for (int mt = 0; mt < 2; mt++)
                af[mt] = *(const bf16x8*)&As[buf][c2 * 2048 + (wm + mt * 16 + lr) * 32 + k8];
#pragma unroll
            for (int nt = 0; nt < 2; nt++)
                bfr[nt] = *(const bf16x8*)&Bs[buf][c2 * 2048 + (wn + nt * 16 + lr) * 32 + k8];
#pragma unroll
            for (int mt = 0; mt < 2; mt++)
#pragma unroll
                for (int nt = 0; nt < 2; nt++)
                    acc[mt][nt] = __builtin_amdgcn_mfma_f32_16x16x32_bf16(
                        af[mt], bfr[nt], acc[mt][nt], 0, 0, 0);
        }
        __syncthreads();
    }
#pragma unroll
    for (int mt = 0; mt < 2; mt++)
#pragma unroll
        for (int nt = 0; nt < 2; nt++) {
            const int row = by * 64 + wm + mt * 16 + quad * 4;
            const int col = bx * 64 + wn + nt * 16 + lr;
#pragma unroll
            for (int r = 0; r < 4; r++)
                Gbf[((size_t)b * CH + row + r) * CH + col] = f2bf(acc[mt][nt][r]);
        }
}

// ---------------------------------------------------------------------------
// 3. colsq: M = B . G (G symmetric -> row-major rows are valid B-operands),
//    colSq[kl] = sum_c' M[kl,c']*B[kl,c'].  64 kl-rows x 128 c'-cols per
//    block, grid (2,36,8)=576 blocks. Two slabs cs0/cs1 (one per c'-half),
//    summed in corr_out -> no global atomics, no memset.
// ---------------------------------------------------------------------------
__global__ __launch_bounds__(256) void colsq(const unsigned short* __restrict__ Bbf,
                                             const unsigned short* __restrict__ Gbf,
                                             float* __restrict__ cs0,
                                             float* __restrict__ cs1) {
    __shared__ unsigned short As[2][4096];   // B-tile: 64 rows x 64k
    __shared__ unsigned short Bs[2][8192];   // G-tile: 128 rows x 64k
    __shared__ float colSqL[64];
    const int tid = threadIdx.x;
    const int bx = blockIdx.x;   // c' half (0/1)
    const int by = blockIdx.y;   // kl tile of 64
    const int b  = blockIdx.z;
    const unsigned short* Ab = Bbf + ((size_t)b * HW2 + by * 64) * CH;
    const unsigned short* Gb = Gbf + ((size_t)b * CH + bx * 128) * CH;
    const int srow = tid >> 2, skcol = (tid & 3) * 8;
    const int wave = tid >> 6, lane = tid & 63;
    const int wm = (wave >> 1) * 32, wn = (wave & 1) * 64;
    const int lr = lane & 15, quad = lane >> 4, k8 = quad * 8;

    f32x4 acc[2][4];
#pragma unroll
    for (int i = 0; i < 2; i++)
#pragma unroll
        for (int j = 0; j < 4; j++) acc[i][j] = (f32x4){0.f, 0.f, 0.f, 0.f};

#define C_STAGE(bufi, kt)                                                      \
    {                                                                          \
        _Pragma("unroll")                                                      \
        for (int c2 = 0; c2 < 2; c2++) {                                       \
            async_copy16(Ab + (size_t)srow * CH + (kt) + c2 * 32 + skcol,      \
                         &As[bufi][c2 * 2048 + tid * 8]);                      \
            _Pragma("unroll")                                                  \
            for (int i = 0; i < 2; i++)                                        \
                async_copy16(Gb + (size_t)(srow + i * 64) * CH + (kt) + c2 * 32 + skcol, \
                             &Bs[bufi][c2 * 4096 + tid * 8 + i * 2048]);       \
        }                                                                      \
    }

    C_STAGE(0, 0);
    __syncthreads();
    for (int t = 0; t < 4; t++) {
        const int buf = t & 1;
        if (t < 3) C_STAGE(buf ^ 1, (t + 1) * 64);
#pragma unroll
        for (int c2 = 0; c2 < 2; c2++) {
            bf16x8 af[2], bfr[4];
#pragma unroll
            for (int mt = 0; mt < 2; mt++)
                af[mt] = *(const bf16x8*)&As[buf][c2 * 2048 + (wm + mt * 16 + lr) * 32 + k8];
#pragma unroll
            for (int nt = 0; nt < 4; nt++)
                bfr[nt] = *(const bf16x8*)&Bs[buf][c2 * 4096 + (wn + nt * 16 + lr) * 32 + k8];
#pragma unroll
            for (int mt = 0; mt < 2; mt++)
#pragma unroll
                for (int nt = 0; nt < 4; nt++)
                    acc[mt][nt] = __builtin_amdgcn_mfma_f32_16x16x32_bf16(
                        af[mt], bfr[nt], acc[mt][nt], 0, 0, 0);
        }
        __syncthreads();
    }

    if (tid < 64) colSqL[tid] = 0.f;
    __syncthreads();
#pragma unroll
    for (int mt = 0; mt < 2; mt++)
#pragma unroll
        for (int r = 0; r < 4; r++) {
            const int lrow = wm + mt * 16 + quad * 4 + r;   // 0..63
            float s = 0.f;
#pragma unroll
            for (int nt = 0; nt < 4; nt++) {
                const int col = bx * 128 + wn + nt * 16 + lr;
                s += acc[mt][nt][r] * bf2f(Ab[(size_t)lrow * CH + col]);
            }
            s += __shfl_xor(s, 1); s += __shfl_xor(s, 2);
            s += __shfl_xor(s, 4); s += __shfl_xor(s, 8);
            if (lr == 0) atomicAdd(&colSqL[lrow], s);   // LDS atomic, 2 waves/row
        }
    __syncthreads();
    if (tid < 64)
        (bx == 0 ? cs0 : cs1)[(size_t)b * HW2 + by * 64 + tid] = colSqL[tid];
}

// ---------------------------------------------------------------------------
// 4. corr_out: 128x256 output tile, BK=32, double-buffered 2-phase.
//    stage(t+1) issued BEFORE compute(t); one __syncthreads per K-step.
// ---------------------------------------------------------------------------
__global__ __launch_bounds__(256, 2) void corr_out(const unsigned short* __restrict__ Abf,
                                                   const unsigned short* __restrict__ Bbf,
                                                   const float* __restrict__ cs0,
                                                   const float* __restrict__ cs1,
                                                   float* __restrict__ out) {
    __shared__ unsigned short As[2][4096];   // 128 rows x 32k per buffer (8 KB)
    __shared__ unsigned short Bs[2][8192];   // 256 rows x 32k per buffer (16 KB)
    const int tid = threadIdx.x;

    // XCD swizzle: batch fastest -> each XCD works ~one batch (L2-resident)
    const int lin = blockIdx.x + 9 * (blockIdx.y + 18 * blockIdx.z);
    const int b  = lin & 7;
    const int r_ = lin >> 3;      // 0..161
    const int bx = r_ % 9;        // kl tile (256 cols)
    const int by = r_ / 9;        // ij tile (128 rows)

    const unsigned short* Ab = Abf + ((size_t)b * HW2 + (size_t)by * 128) * CH;
    const unsigned short* Bb = Bbf + ((size_t)b * HW2 + (size_t)bx * 256) * CH;

    const int srow = tid >> 2, skcol = (tid & 3) * 8;
    const int wave = tid >> 6, lane = tid & 63;
    const int wm = (wave >> 1) * 64, wn = (wave & 1) * 128;
    const int lr = lane & 15, quad = lane >> 4, k8 = quad * 8;

    f32x4 acc[4][8];
#pragma unroll
    for (int i = 0; i < 4; i++)
#pragma unroll
        for (int j = 0; j < 8; j++) acc[i][j] = (f32x4){0.f, 0.f, 0.f, 0.f};

#define O_STAGE(bufi, kt)                                                      \
    {                                                                          \
        _Pragma("unroll")                                                      \
        for (int i = 0; i < 2; i++)                                            \
            async_copy16(Ab + (size_t)(srow + i * 64) * CH + (kt) + skcol,     \
                         &As[bufi][tid * 8 + i * 2048]);                       \
        _Pragma("unroll")                                                      \
        for (int i = 0; i < 4; i++)                                            \
            async_copy16(Bb + (size_t)(srow + i * 64) * CH + (kt) + skcol,     \
                         &Bs[bufi][tid * 8 + i * 2048]);                       \
    }

    O_STAGE(0, 0);
    __syncthreads();
    for (int t = 0; t < 8; t++) {
        const int buf = t & 1;
        if (t < 7) O_STAGE(buf ^ 1, (t + 1) * 32);   // overlap with compute(t)
        bf16x8 af[4], bfr[8];
#pragma unroll
        for (int mt = 0; mt < 4; mt++)
            af[mt] = *(const bf16x8*)&As[buf][(wm + mt * 16 + lr) * 32 + k8];
#pragma unroll
        for (int nt = 0; nt < 8; nt++)
            bfr[nt] = *(const bf16x8*)&Bs[buf][(wn + nt * 16 + lr) * 32 + k8];
#pragma unroll
        for (int mt = 0; mt < 4; mt++)
#pragma unroll
            for (int nt = 0; nt < 8; nt++)
                acc[mt][nt] = __builtin_amdgcn_mfma_f32_16x16x32_bf16(
                    af[mt], bfr[nt], acc[mt][nt], 0, 0, 0);
        __syncthreads();   // drains vmcnt(0): stage(t+1) landed, buf(t) free
    }

    const size_t outBase = (size_t)b * HW2 * HW2;
    const float* c0 = cs0 + (size_t)b * HW2;
    const float* c1 = cs1 + (size_t)b * HW2;
#pragma unroll
    for (int nt = 0; nt < 8; nt++) {
        const int col = bx * 256 + wn + nt * 16 + lr;
        const float rinv = rsqrtf(c0[col] + c1[col]);
#pragma unroll
        for (int mt = 0; mt < 4; mt++) {
            const int row0 = by * 128 + wm + mt * 16 + quad * 4;
            f32x4 v = acc[mt][nt];
#pragma unroll
            for (int r = 0; r < 4; r++)
                out[outBase + (size_t)(row0 + r) * HW2 + col] = v[r] * rinv;
        }
    }
}

extern "C" void kernel_launch(void* const* d_in, const int* in_sizes, int n_in,
                              void* d_out, int out_size, void* d_ws, size_t ws_size,
                              hipStream_t stream) {
    const float* A = (const float*)d_in[0];
    const float* B = (const float*)d_in[1];
    float* out = (float*)d_out;

    unsigned short* Abf  = (unsigned short*)d_ws;          // NELEM bf16
    unsigned short* Bbf  = Abf + NELEM;                    // NELEM bf16
    unsigned short* Atbf = Bbf + NELEM;                    // NELEM bf16 (A^T)
    unsigned short* Gbf  = Atbf + NELEM;                   // 8*256*256 bf16
    float* cs0 = (float*)(Gbf + (size_t)NB * CH * CH);     // 8*2304 f32
    float* cs1 = cs0 + (size_t)NB * HW2;                   // 8*2304 f32

    convert_bf16<<<2304, 256, 0, stream>>>(A, B, Abf, Bbf, Atbf);
    gram<<<dim3(4, 4, NB), 256, 0, stream>>>(Atbf, Gbf);
    colsq<<<dim3(2, 36, NB), 256, 0, stream>>>(Bbf, Gbf, cs0, cs1);
    corr_out<<<dim3(9, 18, NB), 256, 0, stream>>>(Abf, Bbf, cs0, cs1, out);
}

// Round 3
// 250.117 us; speedup vs baseline: 1.0180x; 1.0180x over previous
//
#include <hip/hip_runtime.h>

// B=8, H=W=48 -> 2304 positions, C=256 channels.
// raw[b,ij,kl] = sum_c A[b,ij,c]*B[b,kl,c]
// out = raw / sqrt(sum_ij raw^2)     (reference's 1/C cancels in the norm)
//
// R5: Gram-trick pipeline (colSq[kl] = B[kl]^T (A^T A) B[kl]) with R4's
// cheap support kernels, but corr_out REVERTED to the exact R2 corr_pass
// structure (128x128 tile, BK=64 staged as 2x32, drain-per-step, 16KB LDS,
// plain launch_bounds(256)) -- R4's 128x256/BK=32/(256,2) rewrite measured
// ~2x slower than this proven structure (R4 == R3 algebra).
// 4 dispatches, zero memsets, zero global atomics.

#define HW2 2304
#define CH  256
#define NB  8
#define NELEM (NB * HW2 * CH)   // 4,718,592 per input

typedef __attribute__((ext_vector_type(8))) short bf16x8;   // 8 bf16 = 4 VGPRs
typedef __attribute__((ext_vector_type(4))) float f32x4;    // MFMA acc

static __device__ inline unsigned short f2bf(float f) {
    union { float f; unsigned u; } x; x.f = f;
    unsigned r = x.u + 0x7FFFu + ((x.u >> 16) & 1u);
    return (unsigned short)(r >> 16);
}

static __device__ inline float bf2f(unsigned short u) {
    union { unsigned u; float f; } x; x.u = ((unsigned)u) << 16;
    return x.f;
}

// async global->LDS, 16B per lane (global_load_lds_dwordx4)
static __device__ inline void async_copy16(const void* g, void* l) {
    __builtin_amdgcn_global_load_lds(
        (const __attribute__((address_space(1))) unsigned int*)g,
        (__attribute__((address_space(3))) unsigned int*)l, 16, 0, 0);
}

// ---------------------------------------------------------------------------
// 1. convert: A,B fp32 -> bf16 row-major; additionally A^T (c-major) for gram.
// ---------------------------------------------------------------------------
__global__ __launch_bounds__(256) void convert_bf16(const float* __restrict__ A,
                                                    const float* __restrict__ B,
                                                    unsigned short* __restrict__ Abf,
                                                    unsigned short* __restrict__ Bbf,
                                                    unsigned short* __restrict__ Atbf) {
    __shared__ unsigned short t[64][65];   // +1 pad breaks transpose bank conflicts
    const int blk = blockIdx.x;            // 0..2303
    const bool isA = blk < 1152;
    const int tb = isA ? blk : blk - 1152;
    const int b  = tb / 144;               // 144 tiles per batch = 36 ij x 4 c
    const int tt = tb % 144;
    const int ijt = tt >> 2, ct = tt & 3;
    const size_t base = ((size_t)b * HW2 + (size_t)ijt * 64) * CH + ct * 64;
    const float* src = (isA ? A : B) + base;
    unsigned short* dst = (isA ? Abf : Bbf) + base;
    const int tid = threadIdx.x;
    const int lr = tid & 15, rq = tid >> 4;
#pragma unroll
    for (int p = 0; p < 4; p++) {
        const int row = rq + p * 16;
        float4 v = *(const float4*)(src + (size_t)row * CH + lr * 4);
        ushort4 u;
        u.x = f2bf(v.x); u.y = f2bf(v.y); u.z = f2bf(v.z); u.w = f2bf(v.w);
        *(ushort4*)(dst + (size_t)row * CH + lr * 4) = u;
        if (isA) {
            t[row][lr * 4 + 0] = u.x; t[row][lr * 4 + 1] = u.y;
            t[row][lr * 4 + 2] = u.z; t[row][lr * 4 + 3] = u.w;
        }
    }
    if (isA) {
        __syncthreads();
#pragma unroll
        for (int p = 0; p < 4; p++) {
            const int c = rq + p * 16;     // channel = transposed row
            ushort4 u;
            u.x = t[lr * 4 + 0][c]; u.y = t[lr * 4 + 1][c];
            u.z = t[lr * 4 + 2][c]; u.w = t[lr * 4 + 3][c];
            *(ushort4*)(Atbf + ((size_t)b * CH + (size_t)(ct * 64 + c)) * HW2
                        + (size_t)ijt * 64 + lr * 4) = u;
        }
    }
}

// ---------------------------------------------------------------------------
// 2. gram: G[b] = At . At^T, full K (2304) per block. 64x64 tiles, 128 blocks.
//    Double-buffered 2-phase. Writes bf16 G directly -> no atomics/memset.
// ---------------------------------------------------------------------------
__global__ __launch_bounds__(256) void gram(const unsigned short* __restrict__ Atbf,
                                            unsigned short* __restrict__ Gbf) {
    __shared__ unsigned short As[2][4096];   // [buf][c2*2048 + row*32 + k8]
    __shared__ unsigned short Bs[2][4096];
    const int tid = threadIdx.x;
    const int bx = blockIdx.x, by = blockIdx.y, b = blockIdx.z;
    const unsigned short* Ar = Atbf + ((size_t)b * CH + by * 64) * HW2;
    const unsigned short* Br = Atbf + ((size_t)b * CH + bx * 64) * HW2;
    const int srow = tid >> 2, skcol = (tid & 3) * 8;
    const int wave = tid >> 6, lane = tid & 63;
    const int wm = (wave >> 1) * 32, wn = (wave & 1) * 32;
    const int lr = lane & 15, quad = lane >> 4, k8 = quad * 8;

    f32x4 acc[2][2];
#pragma unroll
    for (int i = 0; i < 2; i++)
#pragma unroll
        for (int j = 0; j < 2; j++) acc[i][j] = (f32x4){0.f, 0.f, 0.f, 0.f};

#define G_STAGE(bufi, kt)                                                      \
    {                                                                          \
        _Pragma("unroll")                                                      \
        for (int c2 = 0; c2 < 2; c2++) {                                       \
            async_copy16(Ar + (size_t)srow * HW2 + (kt) + c2 * 32 + skcol,     \
                         &As[bufi][c2 * 2048 + tid * 8]);                      \
            async_copy16(Br + (size_t)srow * HW2 + (kt) + c2 * 32 + skcol,     \
                         &Bs[bufi][c2 * 2048 + tid * 8]);                      \
        }                                                                      \
    }

    G_STAGE(0, 0);
    __syncthreads();
    for (int t = 0; t < 36; t++) {
        const int buf = t & 1;
        if (t < 35) G_STAGE(buf ^ 1, (t + 1) * 64);
#pragma unroll
        for (int c2 = 0; c2 < 2; c2++) {
            bf16x8 af[2], bfr[2];
#pragma unroll
            for (int mt = 0; mt < 2; mt++)
                af[mt] = *(const bf16x8*)&As[buf][c2 * 2048 + (wm + mt * 16 + lr) * 32 + k8];
#pragma unroll
            for (int nt = 0; nt < 2; nt++)
                bfr[nt] = *(const bf16x8*)&Bs[buf][c2 * 2048 + (wn + nt * 16 + lr) * 32 + k8];
#pragma unroll
            for (int mt = 0; mt < 2; mt++)
#pragma unroll
                for (int nt = 0; nt < 2; nt++)
                    acc[mt][nt] = __builtin_amdgcn_mfma_f32_16x16x32_bf16(
                        af[mt], bfr[nt], acc[mt][nt], 0, 0, 0);
        }
        __syncthreads();
    }
#pragma unroll
    for (int mt = 0; mt < 2; mt++)
#pragma unroll
        for (int nt = 0; nt < 2; nt++) {
            const int row = by * 64 + wm + mt * 16 + quad * 4;
            const int col = bx * 64 + wn + nt * 16 + lr;
#pragma unroll
            for (int r = 0; r < 4; r++)
                Gbf[((size_t)b * CH + row + r) * CH + col] = f2bf(acc[mt][nt][r]);
        }
}

// ---------------------------------------------------------------------------
// 3. colsq: M = B . G (G symmetric -> row-major rows are valid B-operands),
//    colSq[kl] = sum_c' M[kl,c']*B[kl,c'].  64 kl-rows x 128 c'-cols per
//    block, grid (2,36,8)=576 blocks. Two slabs cs0/cs1 (one per c'-half),
//    summed in corr_out -> no global atomics, no memset.
// ---------------------------------------------------------------------------
__global__ __launch_bounds__(256) void colsq(const unsigned short* __restrict__ Bbf,
                                             const unsigned short* __restrict__ Gbf,
                                             float* __restrict__ cs0,
                                             float* __restrict__ cs1) {
    __shared__ unsigned short As[2][4096];   // B-tile: 64 rows x 64k
    __shared__ unsigned short Bs[2][8192];   // G-tile: 128 rows x 64k
    __shared__ float colSqL[64];
    const int tid = threadIdx.x;
    const int bx = blockIdx.x;   // c' half (0/1)
    const int by = blockIdx.y;   // kl tile of 64
    const int b  = blockIdx.z;
    const unsigned short* Ab = Bbf + ((size_t)b * HW2 + by * 64) * CH;
    const unsigned short* Gb = Gbf + ((size_t)b * CH + bx * 128) * CH;
    const int srow = tid >> 2, skcol = (tid & 3) * 8;
    const int wave = tid >> 6, lane = tid & 63;
    const int wm = (wave >> 1) * 32, wn = (wave & 1) * 64;
    const int lr = lane & 15, quad = lane >> 4, k8 = quad * 8;

    f32x4 acc[2][4];
#pragma unroll
    for (int i = 0; i < 2; i++)
#pragma unroll
        for (int j = 0; j < 4; j++) acc[i][j] = (f32x4){0.f, 0.f, 0.f, 0.f};

#define C_STAGE(bufi, kt)                                                      \
    {                                                                          \
        _Pragma("unroll")                                                      \
        for (int c2 = 0; c2 < 2; c2++) {                                       \
            async_copy16(Ab + (size_t)srow * CH + (kt) + c2 * 32 + skcol,      \
                         &As[bufi][c2 * 2048 + tid * 8]);                      \
            _Pragma("unroll")                                                  \
            for (int i = 0; i < 2; i++)                                        \
                async_copy16(Gb + (size_t)(srow + i * 64) * CH + (kt) + c2 * 32 + skcol, \
                             &Bs[bufi][c2 * 4096 + tid * 8 + i * 2048]);       \
        }                                                                      \
    }

    C_STAGE(0, 0);
    __syncthreads();
    for (int t = 0; t < 4; t++) {
        const int buf = t & 1;
        if (t < 3) C_STAGE(buf ^ 1, (t + 1) * 64);
#pragma unroll
        for (int c2 = 0; c2 < 2; c2++) {
            bf16x8 af[2], bfr[4];
#pragma unroll
            for (int mt = 0; mt < 2; mt++)
                af[mt] = *(const bf16x8*)&As[buf][c2 * 2048 + (wm + mt * 16 + lr) * 32 + k8];
#pragma unroll
            for (int nt = 0; nt < 4; nt++)
                bfr[nt] = *(const bf16x8*)&Bs[buf][c2 * 4096 + (wn + nt * 16 + lr) * 32 + k8];
#pragma unroll
            for (int mt = 0; mt < 2; mt++)
#pragma unroll
                for (int nt = 0; nt < 4; nt++)
                    acc[mt][nt] = __builtin_amdgcn_mfma_f32_16x16x32_bf16(
                        af[mt], bfr[nt], acc[mt][nt], 0, 0, 0);
        }
        __syncthreads();
    }

    if (tid < 64) colSqL[tid] = 0.f;
    __syncthreads();
#pragma unroll
    for (int mt = 0; mt < 2; mt++)
#pragma unroll
        for (int r = 0; r < 4; r++) {
            const int lrow = wm + mt * 16 + quad * 4 + r;   // 0..63
            float s = 0.f;
#pragma unroll
            for (int nt = 0; nt < 4; nt++) {
                const int col = bx * 128 + wn + nt * 16 + lr;
                s += acc[mt][nt][r] * bf2f(Ab[(size_t)lrow * CH + col]);
            }
            s += __shfl_xor(s, 1); s += __shfl_xor(s, 2);
            s += __shfl_xor(s, 4); s += __shfl_xor(s, 8);
            if (lr == 0) atomicAdd(&colSqL[lrow], s);   // LDS atomic, 2 waves/row
        }
    __syncthreads();
    if (tid < 64)
        (bx == 0 ? cs0 : cs1)[(size_t)b * HW2 + by * 64 + tid] = colSqL[tid];
}

// ---------------------------------------------------------------------------
// 4. corr_out: EXACT R2 corr_pass structure (128x128 tile, two 32-k chunks
//    per barrier pair, 16KB LDS, plain launch_bounds) -- proven fastest.
//    Only the epilogue differs: denominator = cs0[col] + cs1[col].
// ---------------------------------------------------------------------------
__global__ __launch_bounds__(256) void corr_out(const unsigned short* __restrict__ Abf,
                                                const unsigned short* __restrict__ Bbf,
                                                const float* __restrict__ cs0,
                                                const float* __restrict__ cs1,
                                                float* __restrict__ out) {
    __shared__ unsigned short As[2 * 128 * 32];   // 16 KB
    __shared__ unsigned short Bs[2 * 128 * 32];   // 16 KB

    const int tid = threadIdx.x;

    // XCD swizzle: batch fastest-varying -> each XCD works ~one batch (L2-fit)
    const int lin = blockIdx.x + 18 * (blockIdx.y + 18 * blockIdx.z);
    const int b  = lin & 7;
    const int r_ = lin >> 3;          // 0..323
    const int bx = r_ % 18;           // column tile (kl)
    const int by = r_ / 18;           // row tile (ij)

    const unsigned short* Ab = Abf + ((size_t)b * HW2 + (size_t)by * 128) * CH;
    const unsigned short* Bb = Bbf + ((size_t)b * HW2 + (size_t)bx * 128) * CH;

    const int srow  = tid >> 2;
    const int skcol = (tid & 3) * 8;

    const int wave = tid >> 6;
    const int lane = tid & 63;
    const int wm   = (wave >> 1) * 64;
    const int wn   = (wave & 1) * 64;
    const int lr   = lane & 15;
    const int quad = lane >> 4;
    const int k8   = quad * 8;

    f32x4 acc[4][4];
#pragma unroll
    for (int i = 0; i < 4; i++)
#pragma unroll
        for (int j = 0; j < 4; j++) acc[i][j] = (f32x4){0.f, 0.f, 0.f, 0.f};

    for (int kt = 0; kt < CH; kt += 64) {
#pragma unroll
        for (int c = 0; c < 2; c++) {
            const int kof = kt + c * 32;
#pragma unroll
            for (int i = 0; i < 2; i++) {
                async_copy16(Ab + (size_t)(srow + i * 64) * CH + kof + skcol,
                             &As[c * 4096 + tid * 8 + i * 2048]);
                async_copy16(Bb + (size_t)(srow + i * 64) * CH + kof + skcol,
                             &Bs[c * 4096 + tid * 8 + i * 2048]);
            }
        }
        __syncthreads();   // vmcnt(0) drain + barrier
#pragma unroll
        for (int c = 0; c < 2; c++) {
            bf16x8 af[4], bfr[4];
#pragma unroll
            for (int mt = 0; mt < 4; mt++)
                af[mt] = *(const bf16x8*)&As[c * 4096 + (wm + mt * 16 + lr) * 32 + k8];
#pragma unroll
            for (int nt = 0; nt < 4; nt++)
                bfr[nt] = *(const bf16x8*)&Bs[c * 4096 + (wn + nt * 16 + lr) * 32 + k8];
#pragma unroll
            for (int mt = 0; mt < 4; mt++)
#pragma unroll
                for (int nt = 0; nt < 4; nt++)
                    acc[mt][nt] = __builtin_amdgcn_mfma_f32_16x16x32_bf16(
                        af[mt], bfr[nt], acc[mt][nt], 0, 0, 0);
        }
        __syncthreads();
    }

    const int colBase = bx * 128 + wn;
    const size_t outBase = (size_t)b * HW2 * HW2;
    const float* c0 = cs0 + (size_t)b * HW2;
    const float* c1 = cs1 + (size_t)b * HW2;
#pragma unroll
    for (int nt = 0; nt < 4; nt++) {
        const int col = colBase + nt * 16 + lr;
        const float rinv = rsqrtf(c0[col] + c1[col]);
#pragma unroll
        for (int mt = 0; mt < 4; mt++) {
            const int row0 = by * 128 + wm + mt * 16 + quad * 4;
            f32x4 v = acc[mt][nt];
#pragma unroll
            for (int r = 0; r < 4; r++)
                out[outBase + (size_t)(row0 + r) * HW2 + col] = v[r] * rinv;
        }
    }
}

extern "C" void kernel_launch(void* const* d_in, const int* in_sizes, int n_in,
                              void* d_out, int out_size, void* d_ws, size_t ws_size,
                              hipStream_t stream) {
    const float* A = (const float*)d_in[0];
    const float* B = (const float*)d_in[1];
    float* out = (float*)d_out;

    unsigned short* Abf  = (unsigned short*)d_ws;          // NELEM bf16
    unsigned short* Bbf  = Abf + NELEM;                    // NELEM bf16
    unsigned short* Atbf = Bbf + NELEM;                    // NELEM bf16 (A^T)
    unsigned short* Gbf  = Atbf + NELEM;                   // 8*256*256 bf16
    float* cs0 = (float*)(Gbf + (size_t)NB * CH * CH);     // 8*2304 f32
    float* cs1 = cs0 + (size_t)NB * HW2;                   // 8*2304 f32

    convert_bf16<<<2304, 256, 0, stream>>>(A, B, Abf, Bbf, Atbf);
    gram<<<dim3(4, 4, NB), 256, 0, stream>>>(Atbf, Gbf);
    colsq<<<dim3(2, 36, NB), 256, 0, stream>>>(Bbf, Gbf, cs0, cs1);
    corr_out<<<dim3(18, 18, NB), 256, 0, stream>>>(Abf, Bbf, cs0, cs1, out);
}

// Round 6
// 236.788 us; speedup vs baseline: 1.0753x; 1.0563x over previous
//
#include <hip/hip_runtime.h>

// B=8, H=W=48 -> 2304 positions, C=256 channels.
// raw[b,ij,kl] = sum_c A[b,ij,c]*B[b,kl,c]
// out = raw / sqrt(sum_ij raw^2)     (reference's 1/C cancels in the norm)
//
// R8: single-GEMM persistent pipeline. R6/R7 failed because
// hipLaunchCooperativeKernel never executed (identical absmax = max|ref|
// across both sync variants == all-zero output; JSON absmax=468 = poison
// untouched). Fix: REGULAR <<<512,256>>> launch. Co-residency of all 512
// blocks is guaranteed by construction: LDS 33KB -> 4 blocks/CU,
// __launch_bounds__(256,2) caps VGPR<=256 -> 2 blocks/CU, grid 512 = 2/CU
// on 256 CUs -> all dispatched before any completes. Host-side occupancy
// query as a tripwire; if it reports <2 blocks/CU we run the proven R2
// two-pass fallback instead (no inter-block sync).
//
// Sync (unchanged from R7, RMW-only): contributors atomicAdd colSq partials
// (vmcnt drained by barrier), then fetch_add(cnt) ACQ_REL; tid0 spins on
// acquire loads; readers fetch colSq via fetch_add(+0.0f) RMW which must
// observe the coherence-point value.

#define HW2 2304
#define CH  256
#define NB  8
#define NELEM (NB * HW2 * CH)   // 4,718,592 per input
#define NTILE 2592              // 18*18*8 tiles of 128x128
#define NGRP  144               // NB*18 column groups, 18 members each
#define PBLK  512               // persistent blocks (2/CU, co-resident)

typedef __attribute__((ext_vector_type(8))) short bf16x8;   // 8 bf16 = 4 VGPRs
typedef __attribute__((ext_vector_type(4))) float f32x4;    // MFMA acc

static __device__ inline unsigned short f2bf(float f) {
    union { float f; unsigned u; } x; x.f = f;
    unsigned r = x.u + 0x7FFFu + ((x.u >> 16) & 1u);
    return (unsigned short)(r >> 16);
}

// async global->LDS, 16B per lane (global_load_lds_dwordx4)
static __device__ inline void async_copy16(const void* g, void* l) {
    __builtin_amdgcn_global_load_lds(
        (const __attribute__((address_space(1))) unsigned int*)g,
        (__attribute__((address_space(3))) unsigned int*)l, 16, 0, 0);
}

// ---------------------------------------------------------------------------
// 1. convert: fp32 -> bf16 (A,B row-major) + zero colSqG/cnt for this iter.
// ---------------------------------------------------------------------------
__global__ __launch_bounds__(256) void convert_bf16(const float* __restrict__ A,
                                                    const float* __restrict__ B,
                                                    unsigned short* __restrict__ Abf,
                                                    unsigned short* __restrict__ Bbf,
                                                    float* __restrict__ colSqG,
                                                    int* __restrict__ cnt) {
    const int gidx = blockIdx.x * blockDim.x + threadIdx.x;
    if (gidx < NB * HW2) colSqG[gidx] = 0.0f;     // 18432 floats
    if (gidx < NGRP) cnt[gidx] = 0;
    const int n4 = NELEM / 4;
    for (int i = gidx; i < 2 * n4; i += gridDim.x * blockDim.x) {
        const bool isA = i < n4;
        const int j = isA ? i : i - n4;
        float4 v = (isA ? (const float4*)A : (const float4*)B)[j];
        ushort4 p;
        p.x = f2bf(v.x); p.y = f2bf(v.y); p.z = f2bf(v.z); p.w = f2bf(v.w);
        *(ushort4*)((isA ? Abf : Bbf) + (size_t)j * 4) = p;
    }
}

// ---------------------------------------------------------------------------
// 2a. fused corr: persistent blocks; per tile: R2-proven GEMM -> colSq RMWs
//     -> group-counter sync -> RMW-fetch colSq -> normalize from registers.
// ---------------------------------------------------------------------------
__global__ __launch_bounds__(256, 2) void corr_fused(const unsigned short* __restrict__ Abf,
                                                     const unsigned short* __restrict__ Bbf,
                                                     float* __restrict__ colSqG,
                                                     int* __restrict__ cnt,
                                                     float* __restrict__ out) {
    __shared__ unsigned short As[2 * 128 * 32];   // 16 KB
    __shared__ unsigned short Bs[2 * 128 * 32];   // 16 KB
    __shared__ float colSq[128];

    const int tid = threadIdx.x;
    const int srow  = tid >> 2;
    const int skcol = (tid & 3) * 8;
    const int wave = tid >> 6, lane = tid & 63;
    const int wm = (wave >> 1) * 64, wn = (wave & 1) * 64;
    const int lr = lane & 15, quad = lane >> 4, k8 = quad * 8;

    // XCD swizzle within each round: XCD x (= blockIdx%8) gets 64 consecutive
    // tiles -> ~4 MB working set per XCD per round (L2-fit).
    const int i = blockIdx.x;
    const int T = (i & 7) * 64 + (i >> 3);        // bijective 0..511

    for (int t = T; t < NTILE; t += PBLK) {
        const int g  = t / 18;        // group = (b, bx): shared denominator
        const int by = t % 18;        // member = row tile
        const int b  = g / 18;
        const int bx = g % 18;

        const unsigned short* Ab = Abf + ((size_t)b * HW2 + (size_t)by * 128) * CH;
        const unsigned short* Bb = Bbf + ((size_t)b * HW2 + (size_t)bx * 128) * CH;

        if (tid < 128) colSq[tid] = 0.0f;

        f32x4 acc[4][4];
#pragma unroll
        for (int mi = 0; mi < 4; mi++)
#pragma unroll
            for (int nj = 0; nj < 4; nj++) acc[mi][nj] = (f32x4){0.f, 0.f, 0.f, 0.f};

        for (int kt = 0; kt < CH; kt += 64) {
#pragma unroll
            for (int c = 0; c < 2; c++) {
                const int kof = kt + c * 32;
#pragma unroll
                for (int ii = 0; ii < 2; ii++) {
                    async_copy16(Ab + (size_t)(srow + ii * 64) * CH + kof + skcol,
                                 &As[c * 4096 + tid * 8 + ii * 2048]);
                    async_copy16(Bb + (size_t)(srow + ii * 64) * CH + kof + skcol,
                                 &Bs[c * 4096 + tid * 8 + ii * 2048]);
                }
            }
            __syncthreads();   // vmcnt(0) drain + barrier
#pragma unroll
            for (int c = 0; c < 2; c++) {
                bf16x8 af[4], bfr[4];
#pragma unroll
                for (int mt = 0; mt < 4; mt++)
                    af[mt] = *(const bf16x8*)&As[c * 4096 + (wm + mt * 16 + lr) * 32 + k8];
#pragma unroll
                for (int nt = 0; nt < 4; nt++)
                    bfr[nt] = *(const bf16x8*)&Bs[c * 4096 + (wn + nt * 16 + lr) * 32 + k8];
#pragma unroll
                for (int mt = 0; mt < 4; mt++)
#pragma unroll
                    for (int nt = 0; nt < 4; nt++)
                        acc[mt][nt] = __builtin_amdgcn_mfma_f32_16x16x32_bf16(
                            af[mt], bfr[nt], acc[mt][nt], 0, 0, 0);
            }
            __syncthreads();
        }

        // ---- per-column sum of squares -> LDS -> one global RMW per column
#pragma unroll
        for (int nt = 0; nt < 4; nt++) {
            float s = 0.f;
#pragma unroll
            for (int mt = 0; mt < 4; mt++) {
                f32x4 v = acc[mt][nt];
#pragma unroll
                for (int r = 0; r < 4; r++) s += v[r] * v[r];
            }
            s += __shfl_xor(s, 16);
            s += __shfl_xor(s, 32);
            if (quad == 0) atomicAdd(&colSq[wn + nt * 16 + lr], s);
        }
        __syncthreads();
        if (tid < 128)
            atomicAdd(&colSqG[(size_t)b * HW2 + bx * 128 + tid], colSq[tid]);
        // barrier: every wave drains vmcnt before s_barrier -> all 128 RMWs
        // complete at the coherence point before tid0 bumps cnt.
        __syncthreads();

        // ---- group sync: wait until all 18 row-blocks of (b,bx) contributed
        if (tid == 0) {
            __hip_atomic_fetch_add(&cnt[g], 1, __ATOMIC_ACQ_REL,
                                   __HIP_MEMORY_SCOPE_AGENT);
            while (__hip_atomic_load(&cnt[g], __ATOMIC_ACQUIRE,
                                     __HIP_MEMORY_SCOPE_AGENT) < 18)
                __builtin_amdgcn_s_sleep(8);
        }
        __syncthreads();

        // ---- fetch final colSq via RMW (+0.0f): serializes at the coherence
        // point, cannot read a stale cached line.
        if (tid < 128)
            colSq[tid] = __hip_atomic_fetch_add(
                &colSqG[(size_t)b * HW2 + bx * 128 + tid], 0.0f,
                __ATOMIC_RELAXED, __HIP_MEMORY_SCOPE_AGENT);
        __syncthreads();

        // ---- normalize from registers and write
        const size_t outBase = (size_t)b * HW2 * HW2;
#pragma unroll
        for (int nt = 0; nt < 4; nt++) {
            const int colL = wn + nt * 16 + lr;
            const int col  = bx * 128 + colL;
            const float rinv = rsqrtf(colSq[colL]);
#pragma unroll
            for (int mt = 0; mt < 4; mt++) {
                const int row0 = by * 128 + wm + mt * 16 + quad * 4;
                f32x4 v = acc[mt][nt];
#pragma unroll
                for (int r = 0; r < 4; r++)
                    out[outBase + (size_t)(row0 + r) * HW2 + col] = v[r] * rinv;
            }
        }
        __syncthreads();   // colSq LDS reuse safety before next tile's zeroing
    }
}

// ---------------------------------------------------------------------------
// 2b. fallback: R2's proven two-pass corr (no inter-block sync). Used only
//     if the occupancy tripwire reports <2 blocks/CU for corr_fused.
// ---------------------------------------------------------------------------
template <bool WRITE_OUT>
__global__ __launch_bounds__(256) void corr_pass(const unsigned short* __restrict__ Abf,
                                                 const unsigned short* __restrict__ Bbf,
                                                 float* __restrict__ colSqG,
                                                 float* __restrict__ out) {
    __shared__ unsigned short As[2 * 128 * 32];
    __shared__ unsigned short Bs[2 * 128 * 32];
    __shared__ float colSq[128];

    const int tid = threadIdx.x;
    const int lin = blockIdx.x + 18 * (blockIdx.y + 18 * blockIdx.z);
    const int b  = lin & 7;
    const int r_ = lin >> 3;
    const int bx = r_ % 18;
    const int by = r_ / 18;

    if (!WRITE_OUT && tid < 128) colSq[tid] = 0.0f;

    const unsigned short* Ab = Abf + ((size_t)b * HW2 + (size_t)by * 128) * CH;
    const unsigned short* Bb = Bbf + ((size_t)b * HW2 + (size_t)bx * 128) * CH;

    const int srow  = tid >> 2;
    const int skcol = (tid & 3) * 8;
    const int wave = tid >> 6, lane = tid & 63;
    const int wm = (wave >> 1) * 64, wn = (wave & 1) * 64;
    const int lr = lane & 15, quad = lane >> 4, k8 = quad * 8;

    f32x4 acc[4][4];
#pragma unroll
    for (int i = 0; i < 4; i++)
#pragma unroll
        for (int j = 0; j < 4; j++) acc[i][j] = (f32x4){0.f, 0.f, 0.f, 0.f};

    for (int kt = 0; kt < CH; kt += 64) {
#pragma unroll
        for (int c = 0; c < 2; c++) {
            const int kof = kt + c * 32;
#pragma unroll
            for (int i = 0; i < 2; i++) {
                async_copy16(Ab + (size_t)(srow + i * 64) * CH + kof + skcol,
                             &As[c * 4096 + tid * 8 + i * 2048]);
                async_copy16(Bb + (size_t)(srow + i * 64) * CH + kof + skcol,
                             &Bs[c * 4096 + tid * 8 + i * 2048]);
            }
        }
        __syncthreads();
#pragma unroll
        for (int c = 0; c < 2; c++) {
            bf16x8 af[4], bfr[4];
#pragma unroll
            for (int mt = 0; mt < 4; mt++)
                af[mt] = *(const bf16x8*)&As[c * 4096 + (wm + mt * 16 + lr) * 32 + k8];
#pragma unroll
            for (int nt = 0; nt < 4; nt++)
                bfr[nt] = *(const bf16x8*)&Bs[c * 4096 + (wn + nt * 16 + lr) * 32 + k8];
#pragma unroll
            for (int mt = 0; mt < 4; mt++)
#pragma unroll
                for (int nt = 0; nt < 4; nt++)
                    acc[mt][nt] = __builtin_amdgcn_mfma_f32_16x16x32_bf16(
                        af[mt], bfr[nt], acc[mt][nt], 0, 0, 0);
        }
        __syncthreads();
    }

    const int colBase = bx * 128 + wn;
    if (!WRITE_OUT) {
#pragma unroll
        for (int nt = 0; nt < 4; nt++) {
            float s = 0.f;
#pragma unroll
            for (int mt = 0; mt < 4; mt++) {
                f32x4 v = acc[mt][nt];
#pragma unroll
                for (int r = 0; r < 4; r++) s += v[r] * v[r];
            }
            s += __shfl_xor(s, 16);
            s += __shfl_xor(s, 32);
            if (quad == 0) atomicAdd(&colSq[wn + nt * 16 + lr], s);
        }
        __syncthreads();
        if (tid < 128)
            atomicAdd(&colSqG[(size_t)b * HW2 + bx * 128 + tid], colSq[tid]);
    } else {
        const size_t outBase = (size_t)b * HW2 * HW2;
#pragma unroll
        for (int nt = 0; nt < 4; nt++) {
            const int col = colBase + nt * 16 + lr;
            const float rinv = rsqrtf(colSqG[(size_t)b * HW2 + col]);
#pragma unroll
            for (int mt = 0; mt < 4; mt++) {
                const int row0 = by * 128 + wm + mt * 16 + quad * 4;
                f32x4 v = acc[mt][nt];
#pragma unroll
                for (int r = 0; r < 4; r++)
                    out[outBase + (size_t)(row0 + r) * HW2 + col] = v[r] * rinv;
            }
        }
    }
}

extern "C" void kernel_launch(void* const* d_in, const int* in_sizes, int n_in,
                              void* d_out, int out_size, void* d_ws, size_t ws_size,
                              hipStream_t stream) {
    const float* A = (const float*)d_in[0];
    const float* B = (const float*)d_in[1];
    float* out = (float*)d_out;

    unsigned short* Abf = (unsigned short*)d_ws;           // NELEM bf16
    unsigned short* Bbf = Abf + NELEM;                     // NELEM bf16
    float* colSqG = (float*)(Bbf + NELEM);                 // NB*HW2 f32
    int* cnt = (int*)(colSqG + (size_t)NB * HW2);          // NGRP ints

    // Occupancy tripwire (host-side query, capture-safe, cached). Fused path
    // requires 2 co-resident blocks/CU; launch_bounds+33KB LDS guarantee it,
    // the query only guards against a surprise regression.
    static int occ = -1;
    if (occ < 0) {
        int n = 0;
        hipError_t e = hipOccupancyMaxActiveBlocksPerMultiprocessor(
            &n, (const void*)corr_fused, 256, 0);
        occ = (e == hipSuccess) ? n : 2;   // on query failure trust the static bound
    }

    convert_bf16<<<2048, 256, 0, stream>>>(A, B, Abf, Bbf, colSqG, cnt);

    if (occ >= 2) {
        corr_fused<<<PBLK, 256, 0, stream>>>(Abf, Bbf, colSqG, cnt, out);
    } else {
        dim3 grid(HW2 / 128, HW2 / 128, NB);   // 18 x 18 x 8
        corr_pass<false><<<grid, 256, 0, stream>>>(Abf, Bbf, colSqG, out);
        corr_pass<true><<<grid, 256, 0, stream>>>(Abf, Bbf, colSqG, out);
    }
}